// Round 7
// baseline (364.653 us; speedup 1.0000x reference)
//
#include <hip/hip_runtime.h>
#include <stdint.h>

#define LDS_AS __attribute__((address_space(3)))
#define GLB_AS __attribute__((address_space(1)))

typedef unsigned short bfu;                                   // bf16 bit pattern
typedef __attribute__((ext_vector_type(8))) short short8;     // MFMA A/B frag (8 bf16)
typedef __attribute__((ext_vector_type(4))) float f32x4;      // MFMA C/D frag

static constexpr int B_  = 8192;
static constexpr int D_  = 1024;
static constexpr int E_  = 16;
static constexpr int H_  = 256;
static constexpr int EH_ = E_ * H_;     // 4096

__device__ __forceinline__ bfu f2b(float f) {
  unsigned u = __float_as_uint(f);
  u = (u + 0x7FFFu + ((u >> 16) & 1u)) >> 16;   // RNE, finite data
  return (bfu)u;
}
__device__ __forceinline__ float b2f(bfu b) {
  return __uint_as_float(((unsigned)b) << 16);
}

__device__ __forceinline__ void gload_lds16(const bfu* g, bfu* l) {
  __builtin_amdgcn_global_load_lds((const GLB_AS void*)g, (LDS_AS void*)l, 16, 0, 0);
}

// ---------------- converts ----------------
__global__ void k_f32_to_bf16(const float* __restrict__ in, bfu* __restrict__ out, int n4) {
  int i = blockIdx.x * 256 + threadIdx.x;
  if (i >= n4) return;
  float4 v = reinterpret_cast<const float4*>(in)[i];
  ushort4 o;
  o.x = f2b(v.x); o.y = f2b(v.y); o.z = f2b(v.z); o.w = f2b(v.w);
  reinterpret_cast<ushort4*>(out)[i] = o;
}

// W2 [E][D][H] f32 -> W2t [D][EH_] bf16 with W2t[d][e*256+h] = W2[e][d][h]
__global__ void k_w2_transpose(const float* __restrict__ W2, bfu* __restrict__ W2t) {
  int i = blockIdx.x * 256 + threadIdx.x;   // [0, 16*1024*64)
  if (i >= E_ * D_ * (H_ / 4)) return;
  int h4 = i & 63;
  int d  = (i >> 6) & (D_ - 1);
  int e  = i >> 16;
  float4 v = reinterpret_cast<const float4*>(W2)[((e << 10) | d) * 64 + h4];
  ushort4 o;
  o.x = f2b(v.x); o.y = f2b(v.y); o.z = f2b(v.z); o.w = f2b(v.w);
  reinterpret_cast<ushort4*>(W2t + ((size_t)d << 12) + (e << 8))[h4] = o;
}

// ---------------- router (fp32, exact) ----------------
__global__ __launch_bounds__(256)
void k_router(const float* __restrict__ cond, const float* __restrict__ Wr1,
              const float* __restrict__ br1, const float* __restrict__ Wr2,
              const float* __restrict__ br2, float* __restrict__ route) {
  __shared__ float sW1[128][65];
  __shared__ float sW2[16][129];
  __shared__ float sb1[128], sb2[16];
  __shared__ float sc[2][64];
  __shared__ float srh[2][128];
  const int t = threadIdx.x;
  for (int i = t; i < 128 * 64; i += 256) sW1[i >> 6][i & 63] = Wr1[i];
  for (int i = t; i < 16 * 128; i += 256) sW2[i >> 7][i & 127] = Wr2[i];
  if (t < 128) sb1[t] = br1[t];
  else if (t < 144) sb2[t - 128] = br2[t - 128];
  const int rowBase = blockIdx.x * 32;
  for (int r0 = 0; r0 < 32; r0 += 2) {
    __syncthreads();
    if (t < 128) sc[t >> 6][t & 63] = cond[(size_t)(rowBase + r0 + (t >> 6)) * 64 + (t & 63)];
    __syncthreads();
    {
      const int half = t >> 7, j = t & 127;
      float a = sb1[j];
      #pragma unroll 16
      for (int c = 0; c < 64; ++c) a = fmaf(sc[half][c], sW1[j][c], a);
      srh[half][j] = fmaxf(a, 0.f);
    }
    __syncthreads();
    if (t < 32) {
      const int half = t >> 4, e = t & 15;
      float a = sb2[e];
      #pragma unroll 16
      for (int k = 0; k < 128; ++k) a = fmaf(srh[half][k], sW2[e][k], a);
      float mx = a;
      #pragma unroll
      for (int m = 8; m; m >>= 1) mx = fmaxf(mx, __shfl_xor(mx, m, 16));
      float p = __expf(a - mx);
      float s = p;
      #pragma unroll
      for (int m = 8; m; m >>= 1) s += __shfl_xor(s, m, 16);
      route[(size_t)(rowBase + r0 + half) * 16 + e] = p / s;
    }
  }
}

// ------ 256x256 GEMM-BT, software-pipelined, 1 raw barrier per K-tile ------
// 8 waves (2M x 4N), BK=64, LDS 128KB (2 buf). Per tile, 4 balanced phases:
//   {rd A4-7k0 (4)} MFMA(a,bk0)lo | {rd A0-3k1 + Bk1 (8)} MFMA(a2,bk0)hi |
//   {rd A4-7k1 (4)} MFMA(a,bk1)lo | {vm0; rd next-tile A0-3k0+Bk0 (8)} MFMA(a2,bk1)hi
// s_barrier (raw; tile reads already drained by compiler's counted lgkm);
// STAGE(T+2 -> freed buf) after barrier. vmcnt(0) is ~free: stages issued 1 tile ago.
// EPI=1: bf16 relu(acc+b1)*route -> Hp; EPI=2: split-K x2 (chunk0 f32, chunk1 bf16).

#define WAIT_VM0_SB() do { asm volatile("s_waitcnt vmcnt(0)" ::: "memory"); \
                           __builtin_amdgcn_sched_barrier(0); } while (0)

#define STAGE(matPtr, ld_, rowTile0, half_, tile_, buf_, isA_)                    \
  do {                                                                            \
    const int kel_ = kOff + ((tile_) << 6);                                       \
    bfu* dst_ = lds + ((((buf_) << 2) | ((isA_) ? 0 : 2) | (half_)) << 13);       \
    _Pragma("unroll")                                                             \
    for (int j_ = 0; j_ < 2; ++j_) {                                              \
      int c_ = (j_ << 9) | tid;                                                   \
      int r_ = c_ >> 3;                                                           \
      int sb_ = (((c_ & 7) << 4) ^ ((r_ & 7) << 4));                              \
      gload_lds16((matPtr) + (size_t)((rowTile0) + ((half_) << 7) + r_) * (ld_)   \
                      + kel_ + (sb_ >> 1),                                        \
                  dst_ + c_ * 8);                                                 \
    }                                                                             \
  } while (0)

#define STAGE_TILE(tile_, buf_)                                                   \
  do {                                                                            \
    STAGE(Bm, ldb, bcol, 0, (tile_), (buf_), 0);                                  \
    STAGE(Bm, ldb, bcol, 1, (tile_), (buf_), 0);                                  \
    STAGE(A, lda, brow, 0, (tile_), (buf_), 1);                                   \
    STAGE(A, lda, brow, 1, (tile_), (buf_), 1);                                   \
  } while (0)

#define LDA_FRAG(dst_, buf_, m_, kk_)                                             \
  dst_ = *reinterpret_cast<const short8*>(                                        \
      reinterpret_cast<const char*>(lds + ((((buf_) << 2) | wr) << 13)) +         \
      ((((m_) << 11) + ((kk_) << 6) + aBaseByte) ^ axor))

#define LDB_FRAG(dst_, buf_, n_, kk_)                                             \
  dst_ = *reinterpret_cast<const short8*>(                                        \
      reinterpret_cast<const char*>(lds + ((((buf_) << 2) | 2 | bhalfSel) << 13)) + \
      ((bInner + (((n_) << 11) + ((kk_) << 6) + aBaseByte)) ^ axor))

#define LDA4(dst_, buf_, mbase_, kk_)                                             \
  _Pragma("unroll") for (int m_ = 0; m_ < 4; ++m_)                                \
    LDA_FRAG(dst_[m_], (buf_), (mbase_) + m_, kk_)

#define LDB4(dst_, buf_, kk_)                                                     \
  _Pragma("unroll") for (int n_ = 0; n_ < 4; ++n_)                                \
    LDB_FRAG(dst_[n_], (buf_), n_, kk_)

// 16 MFMA: A-group (4 m-frags) x full B (4 n-frags); each acc hit once
#define MFMAQ(AF_, BF_, mg_)                                                      \
  _Pragma("unroll") for (int mm_ = 0; mm_ < 4; ++mm_)                             \
  _Pragma("unroll") for (int nn_ = 0; nn_ < 4; ++nn_)                             \
    acc[(mg_) * 4 + mm_][nn_] =                                                   \
        __builtin_amdgcn_mfma_f32_16x16x32_bf16(                                  \
            AF_[mm_], BF_[nn_], acc[(mg_) * 4 + mm_][nn_], 0, 0, 0);

// PF_: prefetch next tile's first group across barrier; ST_: stage tile stT_.
#define TILE_BODY(c_, PF_, ST_, stT_)                                             \
  do {                                                                            \
    LDA4(a2_, (c_), 4, 0);                    /* ph1 reads (4)  */                \
    MFMAQ(a_, bk0_, 0);                       /* ph0 MFMA (16)  */                \
    LDA4(a_, (c_), 0, 1);                     /* ph2 reads (8)  */                \
    LDB4(bk1_, (c_), 1);                                                          \
    MFMAQ(a2_, bk0_, 1);                      /* ph1 MFMA (16)  */                \
    LDA4(a2_, (c_), 4, 1);                    /* ph3 reads (4)  */                \
    MFMAQ(a_, bk1_, 0);                       /* ph2 MFMA (16)  */                \
    if (PF_) {                                                                    \
      WAIT_VM0_SB();                          /* tile c^1 staged 1 tile ago */    \
      LDA4(a_, (c_) ^ 1, 0, 0);               /* ph0' reads (8) */                \
      LDB4(bk0_, (c_) ^ 1, 0);                                                    \
    }                                                                             \
    MFMAQ(a2_, bk1_, 1);                      /* ph3 MFMA (16)  */                \
    __builtin_amdgcn_s_barrier();                                                 \
    if (ST_) STAGE_TILE((stT_), (c_));        /* refill freed buf */              \
  } while (0)

template <int EPI>
__global__ __launch_bounds__(512, 2)
void k_gemm8(const bfu* __restrict__ A, int lda,
             const bfu* __restrict__ Bm, int ldb,
             int nkt,                       // K-tiles (per chunk), even, >= 4
             float* __restrict__ outF, bfu* __restrict__ outB, int ldc,
             const float* __restrict__ route, const float* __restrict__ bias1) {
  __shared__ __align__(16) bfu lds[65536];  // 128 KiB: [buf][A/B][half][128*64]
  const int tid = (int)threadIdx.x;
  const int w = tid >> 6, l = tid & 63;
  const int wr = w >> 2, wc = w & 3;
  const int rlane = l & 15, chalf = l >> 4;          // chalf in 0..3
  const int aBaseByte = rlane * 128 + chalf * 16;
  const int axor = (rlane & 7) << 4;
  const int bhalfSel = wc >> 1;
  const int bInner = (wc & 1) << 13;

  const int bid = (int)blockIdx.x;
  const int xcd = bid & 7;
  int brow, bcol, chunk = 0, kOff = 0;
  if (EPI == 1) {
    // grid 512 = 32r x 16c; XCD owns an 8x8 tile square
    const int i = bid >> 3;
    brow = (((xcd >> 1) << 3) + (i >> 3)) << 8;
    bcol = (((xcd & 1) << 3) + (i & 7)) << 8;
  } else {
    // grid 256 = (32r x 4c) x 2 chunks; XCD owns 4-row slab per chunk
    const int i = bid >> 3;
    chunk = i >> 4;
    const int ii = i & 15;
    brow = ((xcd << 2) + (ii >> 2)) << 8;
    bcol = (ii & 3) << 8;
    kOff = chunk * (nkt << 6);
  }

  f32x4 acc[8][4] = {};
  short8 a_[4], a2_[4], bk0_[4], bk1_[4];

  // prologue: stage tiles 0 and 1; full drain once; preload tile0 ph0
  STAGE_TILE(0, 0);
  STAGE_TILE(1, 1);
  __syncthreads();
  LDA4(a_, 0, 0, 0);
  LDB4(bk0_, 0, 0);

  for (int it2 = 0; it2 < (nkt >> 1) - 1; ++it2) {
    const int T = it2 << 1;
    TILE_BODY(0, 1, 1, T + 2);
    TILE_BODY(1, 1, 1, T + 3);
  }
  TILE_BODY(0, 1, 0, 0);     // tile nkt-2: prefetch last tile, no stage
  TILE_BODY(1, 0, 0, 0);     // tile nkt-1: drain
  __syncthreads();           // safety: all counters quiesced; LDS free

  // ---------- all-wave coalesced epilogue via padded LDS bounce ----------
  if (EPI == 1 || chunk == 1) {
    // bf16: 2 slices; LDS view [wrGroup(2)][64 rows][stride 264]
    const int STR = 264;            // 264 bfu = 132 dwords; +4 rows -> +16 banks
    #pragma unroll
    for (int s = 0; s < 2; ++s) {
      #pragma unroll
      for (int ml = 0; ml < 4; ++ml) {
        const int m = s * 4 + ml;
        const int rloc = ml * 16 + chalf * 4;
        #pragma unroll
        for (int n = 0; n < 4; ++n) {
          const int col = wc * 64 + n * 16 + rlane;
          float bz = 0.f;
          if (EPI == 1) bz = bias1[bcol + col];
          #pragma unroll
          for (int j = 0; j < 4; ++j) {
            float v = acc[m][n][j];
            if (EPI == 1) {
              const int rowg = brow + wr * 128 + s * 64 + rloc + j;
              v = fmaxf(v + bz, 0.f) * route[(size_t)rowg * E_ + (bcol >> 8)];
            }
            lds[(wr * 64 + rloc + j) * STR + col] = f2b(v);
          }
        }
      }
      __syncthreads();
      #pragma unroll
      for (int i = 0; i < 8; ++i) {
        const int id = i * 512 + tid;           // 4096 x 16B chunks
        const int row = id >> 5, c16 = id & 31;
        const int g = row >> 6, rl = row & 63;
        *reinterpret_cast<short8*>(outB + (size_t)(brow + g * 128 + s * 64 + rl) * ldc +
                                   bcol + c16 * 8) =
            *reinterpret_cast<const short8*>(lds + row * STR + c16 * 8);
      }
      __syncthreads();
    }
  } else {
    // f32: 4 slices; LDS view [wrGroup(2)][32 rows][stride 268]
    const int STRF = 268;           // 268 dwords; +4 rows -> +16 banks
    float* sF = reinterpret_cast<float*>(lds);
    #pragma unroll
    for (int s = 0; s < 4; ++s) {
      #pragma unroll
      for (int ml = 0; ml < 2; ++ml) {
        const int m = s * 2 + ml;
        const int rloc = ml * 16 + chalf * 4;
        #pragma unroll
        for (int n = 0; n < 4; ++n) {
          const int col = wc * 64 + n * 16 + rlane;
          #pragma unroll
          for (int j = 0; j < 4; ++j)
            sF[(wr * 32 + rloc + j) * STRF + col] = acc[m][n][j];
        }
      }
      __syncthreads();
      #pragma unroll
      for (int i = 0; i < 8; ++i) {
        const int id = i * 512 + tid;           // 4096 x 16B chunks
        const int row = id >> 6, c4 = id & 63;
        const int g = row >> 5, rl = row & 31;
        *reinterpret_cast<float4*>(outF + (size_t)(brow + g * 128 + s * 32 + rl) * ldc +
                                   bcol + c4 * 4) =
            *reinterpret_cast<const float4*>(sF + row * STRF + c4 * 4);
      }
      __syncthreads();
    }
  }
}

// ---------------- reduce: out += P1 + route @ b2 ----------------
__global__ __launch_bounds__(256)
void k_reduce(float* __restrict__ out, const bfu* __restrict__ P1,
              const float* __restrict__ route, const float* __restrict__ b2) {
  __shared__ float sb2[E_ * D_];   // 64 KiB
  for (int i = threadIdx.x; i < E_ * D_; i += 256) sb2[i] = b2[i];
  __syncthreads();
  const int total = (B_ * D_) / 4;
  for (int idx = blockIdx.x * 256 + threadIdx.x; idx < total; idx += gridDim.x * 256) {
    const int b = idx >> 8;
    const int d4 = (idx & 255) * 4;
    float4 o = reinterpret_cast<float4*>(out)[idx];
    ushort4 p = reinterpret_cast<const ushort4*>(P1)[idx];
    o.x += b2f(p.x); o.y += b2f(p.y); o.z += b2f(p.z); o.w += b2f(p.w);
    const float* rr = route + (size_t)b * E_;
    #pragma unroll
    for (int e = 0; e < E_; ++e) {
      const float r = rr[e];
      const float* bb = sb2 + e * D_ + d4;
      o.x = fmaf(r, bb[0], o.x);
      o.y = fmaf(r, bb[1], o.y);
      o.z = fmaf(r, bb[2], o.z);
      o.w = fmaf(r, bb[3], o.w);
    }
    reinterpret_cast<float4*>(out)[idx] = o;
  }
}

// ---------------- launch ----------------
extern "C" void kernel_launch(void* const* d_in, const int* in_sizes, int n_in,
                              void* d_out, int out_size, void* d_ws, size_t ws_size,
                              hipStream_t stream) {
  const float* x    = (const float*)d_in[0];
  const float* cond = (const float*)d_in[1];
  const float* W1   = (const float*)d_in[2];
  const float* b1   = (const float*)d_in[3];
  const float* W2   = (const float*)d_in[4];
  const float* b2   = (const float*)d_in[5];
  const float* Wr1  = (const float*)d_in[6];
  const float* br1  = (const float*)d_in[7];
  const float* Wr2  = (const float*)d_in[8];
  const float* br2  = (const float*)d_in[9];
  float* out = (float*)d_out;

  // ws layout (96.5 MB):
  // [Hp 64MB][W2t 8MB][route 0.5MB][W1b 8MB][xb 16MB (= P1 after GEMM1)]
  char* p = (char*)d_ws;
  bfu*   Hp    = (bfu*)p;                 p += (size_t)B_ * EH_ * 2;
  bfu*   W2t   = (bfu*)p;                 p += (size_t)D_ * EH_ * 2;
  float* route = (float*)p;               p += (size_t)B_ * E_ * 4;
  bfu*   W1b   = (bfu*)p;                 p += (size_t)EH_ * D_ * 2;
  bfu*   xb    = (bfu*)p;                 /* B_*D_*2 = 16MB */
  bfu*   P1b   = xb;                      // alias: xb dead after GEMM1

  k_f32_to_bf16<<<(B_ * D_ / 4 + 255) / 256, 256, 0, stream>>>(x, xb, B_ * D_ / 4);
  k_f32_to_bf16<<<(EH_ * D_ / 4 + 255) / 256, 256, 0, stream>>>(W1, W1b, EH_ * D_ / 4);
  k_w2_transpose<<<(E_ * D_ * (H_ / 4) + 255) / 256, 256, 0, stream>>>(W2, W2t);
  k_router<<<B_ / 32, 256, 0, stream>>>(cond, Wr1, br1, Wr2, br2, route);

  // GEMM1: Hp[8192,4096] = relu(xb @ W1b^T + b1) * route   (512 blocks)
  k_gemm8<1><<<dim3((B_ / 256) * (EH_ / 256)), 512, 0, stream>>>(
      xb, D_, W1b, D_, D_ / 64, nullptr, Hp, EH_, route, b1);

  // GEMM2: out/P1 = Hp @ W2t^T, split-K x2  (256 blocks, 1/CU)
  k_gemm8<2><<<dim3((B_ / 256) * (D_ / 256) * 2), 512, 0, stream>>>(
      Hp, EH_, W2t, EH_, (EH_ / 64) / 2, out, P1b, D_, nullptr, nullptr);

  // out += P1 + route @ b2
  k_reduce<<<2048, 256, 0, stream>>>(out, P1b, route, b2);
}

// Round 9
// 219.215 us; speedup vs baseline: 1.6634x; 1.6634x over previous
//
#include <hip/hip_runtime.h>
#include <stdint.h>

#define LDS_AS __attribute__((address_space(3)))
#define GLB_AS __attribute__((address_space(1)))

typedef unsigned short bfu;                                    // bf16 bit pattern
typedef __attribute__((ext_vector_type(8))) short short8;      // MFMA A/B frag (8 bf16)
typedef __attribute__((ext_vector_type(16))) float f32x16;     // 32x32 MFMA C/D frag

static constexpr int B_  = 8192;
static constexpr int D_  = 1024;
static constexpr int E_  = 16;
static constexpr int H_  = 256;
static constexpr int EH_ = E_ * H_;     // 4096

__device__ __forceinline__ bfu f2b(float f) {
  unsigned u = __float_as_uint(f);
  u = (u + 0x7FFFu + ((u >> 16) & 1u)) >> 16;   // RNE, finite data
  return (bfu)u;
}
__device__ __forceinline__ float b2f(bfu b) {
  return __uint_as_float(((unsigned)b) << 16);
}

__device__ __forceinline__ void gload_lds16(const bfu* g, bfu* l) {
  __builtin_amdgcn_global_load_lds((const GLB_AS void*)g, (LDS_AS void*)l, 16, 0, 0);
}

// ---------------- converts ----------------
__global__ void k_f32_to_bf16(const float* __restrict__ in, bfu* __restrict__ out, int n4) {
  int i = blockIdx.x * 256 + threadIdx.x;
  if (i >= n4) return;
  float4 v = reinterpret_cast<const float4*>(in)[i];
  ushort4 o;
  o.x = f2b(v.x); o.y = f2b(v.y); o.z = f2b(v.z); o.w = f2b(v.w);
  reinterpret_cast<ushort4*>(out)[i] = o;
}

// W2 [E][D][H] f32 -> W2t [D][EH_] bf16 with W2t[d][e*256+h] = W2[e][d][h]
__global__ void k_w2_transpose(const float* __restrict__ W2, bfu* __restrict__ W2t) {
  int i = blockIdx.x * 256 + threadIdx.x;   // [0, 16*1024*64)
  if (i >= E_ * D_ * (H_ / 4)) return;
  int h4 = i & 63;
  int d  = (i >> 6) & (D_ - 1);
  int e  = i >> 16;
  float4 v = reinterpret_cast<const float4*>(W2)[((e << 10) | d) * 64 + h4];
  ushort4 o;
  o.x = f2b(v.x); o.y = f2b(v.y); o.z = f2b(v.z); o.w = f2b(v.w);
  reinterpret_cast<ushort4*>(W2t + ((size_t)d << 12) + (e << 8))[h4] = o;
}

// ---------------- router (fp32, exact) ----------------
__global__ __launch_bounds__(256)
void k_router(const float* __restrict__ cond, const float* __restrict__ Wr1,
              const float* __restrict__ br1, const float* __restrict__ Wr2,
              const float* __restrict__ br2, float* __restrict__ route) {
  __shared__ float sW1[128][65];
  __shared__ float sW2[16][129];
  __shared__ float sb1[128], sb2[16];
  __shared__ float sc[2][64];
  __shared__ float srh[2][128];
  const int t = threadIdx.x;
  for (int i = t; i < 128 * 64; i += 256) sW1[i >> 6][i & 63] = Wr1[i];
  for (int i = t; i < 16 * 128; i += 256) sW2[i >> 7][i & 127] = Wr2[i];
  if (t < 128) sb1[t] = br1[t];
  else if (t < 144) sb2[t - 128] = br2[t - 128];
  const int rowBase = blockIdx.x * 32;
  for (int r0 = 0; r0 < 32; r0 += 2) {
    __syncthreads();
    if (t < 128) sc[t >> 6][t & 63] = cond[(size_t)(rowBase + r0 + (t >> 6)) * 64 + (t & 63)];
    __syncthreads();
    {
      const int half = t >> 7, j = t & 127;
      float a = sb1[j];
      #pragma unroll 16
      for (int c = 0; c < 64; ++c) a = fmaf(sc[half][c], sW1[j][c], a);
      srh[half][j] = fmaxf(a, 0.f);
    }
    __syncthreads();
    if (t < 32) {
      const int half = t >> 4, e = t & 15;
      float a = sb2[e];
      #pragma unroll 16
      for (int k = 0; k < 128; ++k) a = fmaf(srh[half][k], sW2[e][k], a);
      float mx = a;
      #pragma unroll
      for (int m = 8; m; m >>= 1) mx = fmaxf(mx, __shfl_xor(mx, m, 16));
      float p = __expf(a - mx);
      float s = p;
      #pragma unroll
      for (int m = 8; m; m >>= 1) s += __shfl_xor(s, m, 16);
      route[(size_t)(rowBase + r0 + half) * 16 + e] = p / s;
    }
  }
}

// ------ 256x256 GEMM-BT, R6 dbuf skeleton + 32x32x16 MFMA + folded addrs ------
// 8 waves (2M x 4N), per-wave 128x64 out = 4mt x 2nt tiles of 32x32.
// Per K-tile: 24 ds_read_b128 + 32 MFMA(32x32x16), one __syncthreads.
// LDS regions are 16384 B: byte base = buf<<16 | region<<14 (A0,A1,B0,B1).
// A/B frag: row|col = l&31, k = (l>>5)*8 (+ ks*16). C/D: col = l&31,
// row = (r&3) + 8*(r>>2) + 4*(l>>5)  [HW-verified m74/m101 mapping].
// EPI=1: bf16 relu(acc+b1)*route -> Hp; EPI=2: split-K x2 (chunk0 f32, chunk1 bf16).

#define STAGE(matPtr, ld_, rowTile0, half_, tile_, buf_, isA_)                    \
  do {                                                                            \
    const int kel_ = kOff + ((tile_) << 6);                                       \
    bfu* dst_ = lds + ((((buf_) << 2) | ((isA_) ? 0 : 2) | (half_)) << 13);       \
    _Pragma("unroll")                                                             \
    for (int j_ = 0; j_ < 2; ++j_) {                                              \
      int c_ = (j_ << 9) | tid;                                                   \
      int r_ = c_ >> 3;                                                           \
      int sb_ = (((c_ & 7) << 4) ^ ((r_ & 7) << 4));                              \
      gload_lds16((matPtr) + (size_t)((rowTile0) + ((half_) << 7) + r_) * (ld_)   \
                      + kel_ + (sb_ >> 1),                                        \
                  dst_ + c_ * 8);                                                 \
    }                                                                             \
  } while (0)

#define STAGE_TILE(tile_, buf_)                                                   \
  do {                                                                            \
    STAGE(Bm, ldb, bcol, 0, (tile_), (buf_), 0);                                  \
    STAGE(Bm, ldb, bcol, 1, (tile_), (buf_), 0);                                  \
    STAGE(A, lda, brow, 0, (tile_), (buf_), 1);                                   \
    STAGE(A, lda, brow, 1, (tile_), (buf_), 1);                                   \
  } while (0)

// frag reads (BYTE units): runtime base (per ks) + compile-time imm (mt/nt<<12)
#define LDA32(dst_, buf_, ksv_, mt_)                                              \
  dst_ = *reinterpret_cast<const short8*>(                                        \
      ldsC + (((buf_) << 16) | (wr << 14)) + aKs[ksv_] + ((mt_) << 12))

#define LDB32(dst_, buf_, ksv_, nt_)                                              \
  dst_ = *reinterpret_cast<const short8*>(                                        \
      ldsC + ((buf_) << 16) + bKs[ksv_] + ((nt_) << 12))

#define LDA32x4(dst_, buf_, ksv_)                                                 \
  _Pragma("unroll") for (int mt_ = 0; mt_ < 4; ++mt_) LDA32(dst_[mt_], buf_, ksv_, mt_)
#define LDB32x2(dst_, buf_, ksv_)                                                 \
  _Pragma("unroll") for (int nt_ = 0; nt_ < 2; ++nt_) LDB32(dst_[nt_], buf_, ksv_, nt_)

// 8 MFMA, each acc tile hit once per ks-step
#define MFMA8(AF_, BF_)                                                           \
  _Pragma("unroll") for (int mt_ = 0; mt_ < 4; ++mt_)                             \
  _Pragma("unroll") for (int nt_ = 0; nt_ < 2; ++nt_)                             \
    acc[mt_][nt_] = __builtin_amdgcn_mfma_f32_32x32x16_bf16(                      \
        AF_[mt_], BF_[nt_], acc[mt_][nt_], 0, 0, 0);

#define TILE_COMPUTE(c_)                                                          \
  do {                                                                            \
    LDA32x4(aP_, (c_), 0); LDB32x2(bP_, (c_), 0);                                 \
    LDA32x4(aN_, (c_), 1); LDB32x2(bN_, (c_), 1);                                 \
    MFMA8(aP_, bP_);                                                              \
    LDA32x4(aP_, (c_), 2); LDB32x2(bP_, (c_), 2);                                 \
    MFMA8(aN_, bN_);                                                              \
    LDA32x4(aN_, (c_), 3); LDB32x2(bN_, (c_), 3);                                 \
    MFMA8(aP_, bP_);                                                              \
    MFMA8(aN_, bN_);                                                              \
  } while (0)

template <int EPI>
__global__ __launch_bounds__(512, 2)
void k_gemm8(const bfu* __restrict__ A, int lda,
             const bfu* __restrict__ Bm, int ldb,
             int nkt,                       // K-tiles (per chunk), even, >= 2
             float* __restrict__ outF, bfu* __restrict__ outB, int ldc,
             const float* __restrict__ route, const float* __restrict__ bias1) {
  __shared__ __align__(16) bfu lds[65536];  // 128 KiB: [buf][A/B][half][128*64]
  const char* ldsC = reinterpret_cast<const char*>(lds);
  const int tid = (int)threadIdx.x;
  const int w = tid >> 6, l = tid & 63;
  const int wr = w >> 2, wc = w & 3;
  const int rlane = l & 15;                 // (unused in core, kept for clarity)
  (void)rlane;
  const int l31 = l & 31, lhi = l >> 5;
  const unsigned axor = (unsigned)((l & 7) << 4);
  const int bhalfSel = wc >> 1;
  const int bInner = (wc & 1) << 13;        // 64-col block within B region (bytes)

  // per-ks LDS byte bases; kterm bits 4-6 XOR-swizzled to match STAGE layout
  unsigned aKs[4], bKs[4];
  #pragma unroll
  for (int ks = 0; ks < 4; ++ks) {
    const unsigned kterm = ((unsigned)((ks << 5) | (lhi << 4))) ^ axor;
    aKs[ks] = (unsigned)(l31 * 128) + kterm;
    bKs[ks] = (unsigned)(((2 | bhalfSel) << 14) + bInner + l31 * 128) + kterm;
  }

  const int bid = (int)blockIdx.x;
  const int xcd = bid & 7;
  int brow, bcol, chunk = 0, kOff = 0;
  if (EPI == 1) {
    // grid 512 = 32r x 16c; XCD owns an 8x8 tile square
    const int i = bid >> 3;
    brow = (((xcd >> 1) << 3) + (i >> 3)) << 8;
    bcol = (((xcd & 1) << 3) + (i & 7)) << 8;
  } else {
    // grid 256 = (32r x 4c) x 2 chunks; XCD owns 4-row slab per chunk
    const int i = bid >> 3;
    chunk = i >> 4;
    const int ii = i & 15;
    brow = ((xcd << 2) + (ii >> 2)) << 8;
    bcol = (ii & 3) << 8;
    kOff = chunk * (nkt << 6);
  }

  f32x16 acc[4][2] = {};
  short8 aP_[4], aN_[4], bP_[2], bN_[2];

  // prologue: stage tile 0 into buf0; barrier drains it (one-time HBM stall)
  STAGE_TILE(0, 0);
  __syncthreads();

  for (int it = 0; it < (nkt >> 1); ++it) {
    const int T = it << 1;
    STAGE_TILE(T + 1, 1);                  // T+1 < nkt always (nkt even)
    TILE_COMPUTE(0);
    __syncthreads();
    if (T + 2 < nkt) STAGE_TILE(T + 2, 0); // uniform scalar branch
    TILE_COMPUTE(1);
    __syncthreads();
  }

  // ---------- all-wave coalesced epilogue via padded LDS bounce ----------
  if (EPI == 1 || chunk == 1) {
    // bf16: 2 slices of (2 wr x 64 rows); LDS stride 264 bfu
    const int STR = 264;
    #pragma unroll
    for (int s = 0; s < 2; ++s) {
      #pragma unroll
      for (int mt2 = 0; mt2 < 2; ++mt2) {
        const int mt = s * 2 + mt2;
        float bz0 = 0.f, bz1 = 0.f;
        if (EPI == 1) {
          bz0 = bias1[bcol + wc * 64 + l31];
          bz1 = bias1[bcol + wc * 64 + 32 + l31];
        }
        #pragma unroll
        for (int r = 0; r < 16; ++r) {
          const int rloc = mt2 * 32 + (r & 3) + 8 * (r >> 2) + 4 * lhi;
          float rt = 1.f;
          if (EPI == 1) {
            const int rowg = brow + wr * 128 + s * 64 + rloc;
            rt = route[(size_t)rowg * E_ + (bcol >> 8)];
          }
          float v0 = acc[mt][0][r], v1 = acc[mt][1][r];
          if (EPI == 1) {
            v0 = fmaxf(v0 + bz0, 0.f) * rt;
            v1 = fmaxf(v1 + bz1, 0.f) * rt;
          }
          lds[(wr * 64 + rloc) * STR + wc * 64 + l31] = f2b(v0);
          lds[(wr * 64 + rloc) * STR + wc * 64 + 32 + l31] = f2b(v1);
        }
      }
      __syncthreads();
      #pragma unroll
      for (int i = 0; i < 8; ++i) {
        const int id = i * 512 + tid;           // 4096 x 16B chunks
        const int row = id >> 5, c16 = id & 31;
        const int g = row >> 6, rl = row & 63;
        *reinterpret_cast<short8*>(outB + (size_t)(brow + g * 128 + s * 64 + rl) * ldc +
                                   bcol + c16 * 8) =
            *reinterpret_cast<const short8*>(lds + row * STR + c16 * 8);
      }
      __syncthreads();
    }
  } else {
    // f32: 4 slices of (2 wr x 32 rows); LDS stride 268 f32
    const int STRF = 268;
    float* sF = reinterpret_cast<float*>(lds);
    #pragma unroll
    for (int s = 0; s < 4; ++s) {
      #pragma unroll
      for (int r = 0; r < 16; ++r) {
        const int rloc = (r & 3) + 8 * (r >> 2) + 4 * lhi;
        sF[(wr * 32 + rloc) * STRF + wc * 64 + l31] = acc[s][0][r];
        sF[(wr * 32 + rloc) * STRF + wc * 64 + 32 + l31] = acc[s][1][r];
      }
      __syncthreads();
      #pragma unroll
      for (int i = 0; i < 8; ++i) {
        const int id = i * 512 + tid;           // 4096 x 16B chunks
        const int row = id >> 6, c4 = id & 63;
        const int g = row >> 5, rl = row & 31;
        *reinterpret_cast<float4*>(outF + (size_t)(brow + g * 128 + s * 32 + rl) * ldc +
                                   bcol + c4 * 4) =
            *reinterpret_cast<const float4*>(sF + row * STRF + c4 * 4);
      }
      __syncthreads();
    }
  }
}

// ---------------- reduce: out += P1 + route @ b2 ----------------
__global__ __launch_bounds__(256)
void k_reduce(float* __restrict__ out, const bfu* __restrict__ P1,
              const float* __restrict__ route, const float* __restrict__ b2) {
  __shared__ float sb2[E_ * D_];   // 64 KiB
  for (int i = threadIdx.x; i < E_ * D_; i += 256) sb2[i] = b2[i];
  __syncthreads();
  const int total = (B_ * D_) / 4;
  for (int idx = blockIdx.x * 256 + threadIdx.x; idx < total; idx += gridDim.x * 256) {
    const int b = idx >> 8;
    const int d4 = (idx & 255) * 4;
    float4 o = reinterpret_cast<float4*>(out)[idx];
    ushort4 p = reinterpret_cast<const ushort4*>(P1)[idx];
    o.x += b2f(p.x); o.y += b2f(p.y); o.z += b2f(p.z); o.w += b2f(p.w);
    const float* rr = route + (size_t)b * E_;
    #pragma unroll
    for (int e = 0; e < E_; ++e) {
      const float r = rr[e];
      const float* bb = sb2 + e * D_ + d4;
      o.x = fmaf(r, bb[0], o.x);
      o.y = fmaf(r, bb[1], o.y);
      o.z = fmaf(r, bb[2], o.z);
      o.w = fmaf(r, bb[3], o.w);
    }
    reinterpret_cast<float4*>(out)[idx] = o;
  }
}

// ---------------- launch ----------------
extern "C" void kernel_launch(void* const* d_in, const int* in_sizes, int n_in,
                              void* d_out, int out_size, void* d_ws, size_t ws_size,
                              hipStream_t stream) {
  const float* x    = (const float*)d_in[0];
  const float* cond = (const float*)d_in[1];
  const float* W1   = (const float*)d_in[2];
  const float* b1   = (const float*)d_in[3];
  const float* W2   = (const float*)d_in[4];
  const float* b2   = (const float*)d_in[5];
  const float* Wr1  = (const float*)d_in[6];
  const float* br1  = (const float*)d_in[7];
  const float* Wr2  = (const float*)d_in[8];
  const float* br2  = (const float*)d_in[9];
  float* out = (float*)d_out;

  // ws layout (96.5 MB):
  // [Hp 64MB][W2t 8MB][route 0.5MB][W1b 8MB][xb 16MB (= P1 after GEMM1)]
  char* p = (char*)d_ws;
  bfu*   Hp    = (bfu*)p;                 p += (size_t)B_ * EH_ * 2;
  bfu*   W2t   = (bfu*)p;                 p += (size_t)D_ * EH_ * 2;
  float* route = (float*)p;               p += (size_t)B_ * E_ * 4;
  bfu*   W1b   = (bfu*)p;                 p += (size_t)EH_ * D_ * 2;
  bfu*   xb    = (bfu*)p;                 /* B_*D_*2 = 16MB */
  bfu*   P1b   = xb;                      // alias: xb dead after GEMM1

  k_f32_to_bf16<<<(B_ * D_ / 4 + 255) / 256, 256, 0, stream>>>(x, xb, B_ * D_ / 4);
  k_f32_to_bf16<<<(EH_ * D_ / 4 + 255) / 256, 256, 0, stream>>>(W1, W1b, EH_ * D_ / 4);
  k_w2_transpose<<<(E_ * D_ * (H_ / 4) + 255) / 256, 256, 0, stream>>>(W2, W2t);
  k_router<<<B_ / 32, 256, 0, stream>>>(cond, Wr1, br1, Wr2, br2, route);

  // GEMM1: Hp[8192,4096] = relu(xb @ W1b^T + b1) * route   (512 blocks)
  k_gemm8<1><<<dim3((B_ / 256) * (EH_ / 256)), 512, 0, stream>>>(
      xb, D_, W1b, D_, D_ / 64, nullptr, Hp, EH_, route, b1);

  // GEMM2: out/P1 = Hp @ W2t^T, split-K x2  (256 blocks, 1/CU)
  k_gemm8<2><<<dim3((B_ / 256) * (D_ / 256) * 2), 512, 0, stream>>>(
      Hp, EH_, W2t, EH_, (EH_ / 64) / 2, out, P1b, D_, nullptr, nullptr);

  // out += P1 + route @ b2
  k_reduce<<<2048, 256, 0, stream>>>(out, P1b, route, b2);
}